// Round 4
// baseline (297.068 us; speedup 1.0000x reference)
//
#include <hip/hip_runtime.h>

typedef unsigned short u16;
typedef unsigned int u32;
typedef __attribute__((ext_vector_type(8))) short short8;
typedef __attribute__((ext_vector_type(4))) float fx4;

#define LOG2E 1.44269504088896340736f

__device__ __forceinline__ u16 f2bf(float f) {
    unsigned int u = __float_as_uint(f);
    u += 0x7fffu + ((u >> 16) & 1u);
    return (u16)(u >> 16);
}

__device__ __forceinline__ float bf2f(u16 v) {
    u32 u = ((u32)v) << 16;
    return __uint_as_float(u);
}

// pack two fp32 -> two truncated bf16 in one u32 (v_perm_b32)
__device__ __forceinline__ u32 pack_bf2(float lo, float hi) {
    return __builtin_amdgcn_perm(__float_as_uint(hi), __float_as_uint(lo), 0x07060302u);
}

__device__ __forceinline__ float fast_exp2(float x) {
#if __has_builtin(__builtin_amdgcn_exp2f)
    return __builtin_amdgcn_exp2f(x);
#else
    return exp2f(x);
#endif
}

__device__ __forceinline__ fx4 mfma16(short8 a, short8 b, fx4 c) {
    return __builtin_amdgcn_mfma_f32_16x16x32_bf16(a, b, c, 0, 0, 0);
}

__device__ __forceinline__ void gload_lds16(const u16* g, u16* l) {
    __builtin_amdgcn_global_load_lds(
        (const __attribute__((address_space(1))) void*)g,
        (__attribute__((address_space(3))) void*)l, 16, 0, 0);
}

// ---------------------------------------------------------------------------
// Fused LayerNorm + weight transpose (heterogeneous grid, 6144 blocks):
//   blocks 0..2047:   LN, 4 rows each (one wave per row, shuffle-only).
//   blocks 2048..6143: 32x32 transpose tiles of [Wq|Wkv|Wo] -> Wall_t.
// ---------------------------------------------------------------------------
__global__ __launch_bounds__(256) void ln_wt_kernel(
    const float* __restrict__ x, const float* __restrict__ gamma,
    const float* __restrict__ beta, u16* __restrict__ yb,
    const float* __restrict__ Wq, const float* __restrict__ Wkv,
    const float* __restrict__ Wo, u16* __restrict__ Wt) {
    int blk = blockIdx.x;
    if (blk < 2048) {
        int wave = threadIdx.x >> 6, lane = threadIdx.x & 63;
        int row = (blk << 2) + wave;
        const float* xr = x + ((size_t)row << 10);
        float4 v[4];
        float s = 0.0f, sq = 0.0f;
#pragma unroll
        for (int i = 0; i < 4; ++i) {
            v[i] = *(const float4*)(xr + (i << 8) + (lane << 2));
            s  += v[i].x + v[i].y + v[i].z + v[i].w;
            sq += v[i].x * v[i].x + v[i].y * v[i].y + v[i].z * v[i].z + v[i].w * v[i].w;
        }
#pragma unroll
        for (int o = 32; o > 0; o >>= 1) {
            s  += __shfl_xor(s, o, 64);
            sq += __shfl_xor(sq, o, 64);
        }
        float mean = s * (1.0f / 1024.0f);
        float var  = sq * (1.0f / 1024.0f) - mean * mean;
        float rstd = rsqrtf(var + 1e-3f);
#pragma unroll
        for (int i = 0; i < 4; ++i) {
            int off = (i << 8) + (lane << 2);
            float4 g  = *(const float4*)(gamma + off);
            float4 bb = *(const float4*)(beta + off);
            float4 y;
            y.x = (v[i].x - mean) * rstd * g.x + bb.x;
            y.y = (v[i].y - mean) * rstd * g.y + bb.y;
            y.z = (v[i].z - mean) * rstd * g.z + bb.z;
            y.w = (v[i].w - mean) * rstd * g.w + bb.w;
            unsigned long long p = (unsigned long long)f2bf(y.x)
                | ((unsigned long long)f2bf(y.y) << 16)
                | ((unsigned long long)f2bf(y.z) << 32)
                | ((unsigned long long)f2bf(y.w) << 48);
            *(unsigned long long*)(yb + ((size_t)row << 10) + off) = p;
        }
    } else {
        int wtb = blk - 2048;
        int n0 = (wtb & 127) << 5;   // 0..4095
        int k0 = (wtb >> 7) << 5;    // 0..1023
        const float* W; int sn0, SN;
        if (n0 < 1024)      { W = Wq;  sn0 = n0;        SN = 1024; }
        else if (n0 < 3072) { W = Wkv; sn0 = n0 - 1024; SN = 2048; }
        else                { W = Wo;  sn0 = n0 - 3072; SN = 1024; }
        __shared__ float tile[32][33];
        int tx = threadIdx.x & 31, ty = threadIdx.x >> 5;  // ty 0..7
#pragma unroll
        for (int r = 0; r < 4; ++r)
            tile[ty + r * 8][tx] = W[(size_t)(k0 + ty + r * 8) * SN + sn0 + tx];
        __syncthreads();
#pragma unroll
        for (int r = 0; r < 4; ++r)
            Wt[(size_t)(n0 + ty + r * 8) * 1024 + k0 + tx] = f2bf(tile[tx][ty + r * 8]);
    }
}

// ---------------------------------------------------------------------------
// QKV projection GEMM, 256x256 tile, 8-phase deep-pipelined schedule
// (T2 zero-conflict XOR swizzle + T3/T4 counted-vmcnt phases + T5 setprio).
// C[8192,3072] = A[8192,1024] @ Bt[3072,1024]^T.
// 8 waves (2Mx4N), wave tile 128x64, BK=64, LDS 128KB (2 dbuf x (A+B) K-tile).
// Per K-tile: 4 phases, quadrant order (Ah0,Bh0)(Ah0,Bh1)(Ah1,Bh0)(Ah1,Bh1);
// A-fragments are held across the two phases sharing a half (32 ds_read/tile).
// Stage slots (tile t): p1->A(t+1)h1, p2->B(t+1)h1 (into buf nxt);
//                       p3->A(t+2)h0, p4->B(t+2)h0 (into buf cur).
// vmcnt ledger (per wave): before t.p4's wait, outstanding = 12
// {A(t+1)h0,B(t+1)h0 (leftover 4), A(t+1)h1, B(t+1)h1, A(t+2)h0, B(t+2)h0};
// vmcnt(4) drains the 8 oldest = ALL of tile t+1, leaves 4 in flight.
// Barrier #1 of p4 then makes tile t+1 visible chip-wide before any read.
// WAR safety: each staged region's last readers are >=1 asm-barrier upstream
// of the stage issue, and those reads completed at their phase's lgkmcnt(0).
// CRITICAL (v3): barriers are RAW ASM s_barrier, not the builtin. The
// waitcnt-insertion pass forces s_waitcnt vmcnt(0) before a *visible*
// s_barrier while LDS-DMA is outstanding -> one full HBM drain per phase
// (v1/v2 regression: 2060 cy/phase vs 950 structural, MfmaUtil 18%).
// Raw asm hides the barrier from the pass; counted vmcnt does the sync.
// sched_barrier(0) fences pin loads/MFMA inside their phase.
// Epilogue: cols<1024 Q (bias+qscale), 1024..2047 K (bias), >=2048 V ->
// fused transpose+k'-permute scatter into Vt.
// ---------------------------------------------------------------------------
__global__ __launch_bounds__(512, 2) void gemm_qkv8(
    const u16* __restrict__ A, const u16* __restrict__ Bt,
    const float* __restrict__ bq, const float* __restrict__ bkv,
    u16* __restrict__ Cb, u16* __restrict__ Vt, float qscale) {
    __shared__ __align__(16) u16 sA[2][256 * 64];
    __shared__ __align__(16) u16 sB[2][256 * 64];

    // bijective XCD swizzle: 384 blocks, 8 XCDs, 48 blocks/XCD (4 m x 12 n)
    int id = blockIdx.x;
    int swz = (id & 7) * 48 + (id >> 3);
    int mtile = swz / 12, ntile = swz - mtile * 12;
    int m0 = mtile << 8, n0 = ntile << 8;

    int tid = threadIdx.x, lane = tid & 63, wave = tid >> 6;
    int quad = lane >> 4, l15 = lane & 15;
    int srow = lane >> 3, gseg = (lane & 7) ^ srow;
    int wm = wave >> 2, wn = wave & 3;   // 2 x 4 wave grid

    fx4 acc[8][4];
    fx4 zero = {0.0f, 0.0f, 0.0f, 0.0f};
#pragma unroll
    for (int i = 0; i < 8; ++i)
#pragma unroll
        for (int j = 0; j < 4; ++j) acc[i][j] = zero;

    // stage one half-tile (128 rows x 64 k) : 2 gload_lds w16 per thread.
    // chunk = 8 rows x 64 cols (1KB), wave w stages chunks w and 8+w.
    // global source pre-swizzled: slot s of row r holds k-seg s^(r&7).
    auto stA = [&](int kt, int half, int b) {
#pragma unroll
        for (int rnd = 0; rnd < 2; ++rnd) {
            int lr = (half << 7) + (((rnd << 3) + wave) << 3);
            gload_lds16(A + (size_t)(m0 + lr + srow) * 1024 + (kt << 6) + (gseg << 3),
                        &sA[b][lr << 6]);
        }
    };
    auto stB = [&](int kt, int half, int b) {
#pragma unroll
        for (int rnd = 0; rnd < 2; ++rnd) {
            int lr = (half << 7) + (((rnd << 3) + wave) << 3);
            gload_lds16(Bt + (size_t)(n0 + lr + srow) * 1024 + (kt << 6) + (gseg << 3),
                        &sB[b][lr << 6]);
        }
    };

    const int NT = 16;   // K=1024 / BK=64

    // prologue: tile0 complete (4 halves) + tile1 h0 halves -> 12 loads.
    stA(0, 0, 0); stA(0, 1, 0); stB(0, 0, 0); stB(0, 1, 0);
    stA(1, 0, 1); stB(1, 0, 1);
    asm volatile("s_waitcnt vmcnt(4)");   // own tile0 loads landed
    __builtin_amdgcn_sched_barrier(0);
    asm volatile("s_barrier");            // all waves' tile0 loads landed
    __builtin_amdgcn_sched_barrier(0);    // pin: no LDS read above barrier

#define LOADA(half)                                                          \
    _Pragma("unroll") for (int j = 0; j < 4; ++j) {                          \
        int r = ((half) << 7) + (wm << 6) + (j << 4) + l15;                  \
        _Pragma("unroll") for (int kk = 0; kk < 2; ++kk)                     \
            afr[j][kk] = *(const short8*)&sAc[(r << 6) +                     \
                ((((kk << 2) + quad) ^ (r & 7)) << 3)];                      \
    }
#define LOADB(half)                                                          \
    _Pragma("unroll") for (int n = 0; n < 2; ++n) {                          \
        int r = ((half) << 7) + (wn << 5) + (n << 4) + l15;                  \
        _Pragma("unroll") for (int kk = 0; kk < 2; ++kk)                     \
            bfr[n][kk] = *(const short8*)&sBc[(r << 6) +                     \
                ((((kk << 2) + quad) ^ (r & 7)) << 3)];                      \
    }
#define BARMFMA(QM, QN)                                                      \
    __builtin_amdgcn_sched_barrier(0);                                       \
    asm volatile("s_barrier");                                               \
    asm volatile("s_waitcnt lgkmcnt(0)");                                    \
    __builtin_amdgcn_sched_barrier(0);                                       \
    __builtin_amdgcn_s_setprio(1);                                           \
    _Pragma("unroll") for (int kk = 0; kk < 2; ++kk)                         \
        _Pragma("unroll") for (int j = 0; j < 4; ++j)                        \
            _Pragma("unroll") for (int n = 0; n < 2; ++n)                    \
                acc[((QM) << 2) + j][((QN) << 1) + n] = mfma16(              \
                    afr[j][kk], bfr[n][kk],                                  \
                    acc[((QM) << 2) + j][((QN) << 1) + n]);                  \
    __builtin_amdgcn_s_setprio(0);                                           \
    __builtin_amdgcn_sched_barrier(0);                                       \
    asm volatile("s_barrier");                                               \
    __builtin_amdgcn_sched_barrier(0);

#pragma unroll 2
    for (int t = 0; t < NT; ++t) {
        int cur = t & 1, nxt = cur ^ 1;
        bool s1 = (t + 1 < NT), s2 = (t + 2 < NT);
        const u16* sAc = sA[cur];
        const u16* sBc = sB[cur];
        short8 afr[4][2], bfr[2][2];
        // ---- p1: quadrant (Ah0, Bh0) ----
        LOADA(0); LOADB(0);
        if (s1) stA(t + 1, 1, nxt);
        BARMFMA(0, 0);
        // ---- p2: quadrant (Ah0, Bh1) -- afr reused ----
        LOADB(1);
        if (s1) stB(t + 1, 1, nxt);
        BARMFMA(0, 1);
        // ---- p3: quadrant (Ah1, Bh0) ----
        LOADA(1); LOADB(0);
        if (s2) stA(t + 2, 0, cur);
        BARMFMA(1, 0);
        // ---- p4: quadrant (Ah1, Bh1) -- afr reused; per-tile vmcnt ----
        LOADB(1);
        if (s2) stB(t + 2, 0, cur);
        if (s1) {
            if (s2) { asm volatile("s_waitcnt vmcnt(4)"); }
            else    { asm volatile("s_waitcnt vmcnt(0)"); }
        }
        BARMFMA(1, 1);
    }
#undef LOADA
#undef LOADB
#undef BARMFMA

    // ---- epilogue ----
    bool vregion = (n0 >= 2048);
#pragma unroll
    for (int jm = 0; jm < 8; ++jm)
#pragma unroll
        for (int jn = 0; jn < 4; ++jn) {
            int colb = n0 + ((jn & 2) << 6) + (wn << 5) + ((jn & 1) << 4) + l15;
            int rowb = m0 + ((jm & 4) << 5) + (wm << 6) + ((jm & 3) << 4) + (quad << 2);
            if (!vregion) {
                float bias = (colb < 1024) ? bq[colb] : bkv[colb - 1024];
#pragma unroll
                for (int r = 0; r < 4; ++r) {
                    float v = acc[jm][jn][r] + bias;
                    if (colb < 1024) v *= qscale;
                    Cb[(size_t)(rowb + r) * 3072 + colb] = f2bf(v);
                }
            } else {
                float bias = bkv[colb - 1024];
                int h = (colb - 2048) >> 6, d = colb & 63;
#pragma unroll
                for (int r = 0; r < 4; ++r) {
                    int row = rowb + r;
                    int bb = row >> 10, k = row & 1023;
                    int kt2 = k >> 6, kin = k & 63;
                    int kp = ((kin & 15) << 2) | (kin >> 4);
                    Vt[(size_t)((((bb << 4) + h) << 6) + d) * 1024
                       + (kt2 << 6) + kp] = f2bf(acc[jm][jn][r] + bias);
                }
            }
        }
}

// ---------------------------------------------------------------------------
// GEMM: C[M,N] = A[M,K] @ Bt[N,K]^T + bias.  128x128 block tile (WMT=4),
// 2x2 waves of 64x64, 16x16x32 mfma, BK=64, global_load_lds w16 staging,
// XOR-swizzled LDS (zero-conflict 16-row fragment reads).
// MODE 1 (O proj): fp32 out + bias bq + bf16 residual.
// ---------------------------------------------------------------------------
template <int MODE, int WMT>
__global__ __launch_bounds__(256) void gemm_bt(
    const u16* __restrict__ A, const u16* __restrict__ Bt,
    const float* __restrict__ bq, const float* __restrict__ bkv,
    const u16* __restrict__ resb, float* __restrict__ Cf, u16* __restrict__ Cb,
    u16* __restrict__ Vt, int M, int N, int K, float qscale) {
    __shared__ __align__(16) u16 sA[WMT * 32 * 64];
    __shared__ __align__(16) u16 sB[128 * 64];
    int m0 = blockIdx.y * (WMT * 32), n0 = blockIdx.x << 7;
    int tid = threadIdx.x, lane = tid & 63, wave = tid >> 6;
    int quad = lane >> 4, l15 = lane & 15, swr = lane & 7;
    int wm = (wave >> 1) * (WMT * 16), wn = (wave & 1) << 6;
    int srow = lane >> 3;
    int gseg = (lane & 7) ^ srow;

    fx4 acc[WMT][4];
    fx4 zero = {0.0f, 0.0f, 0.0f, 0.0f};
#pragma unroll
    for (int i = 0; i < WMT; ++i)
#pragma unroll
        for (int j = 0; j < 4; ++j) acc[i][j] = zero;

    for (int k0 = 0; k0 < K; k0 += 64) {
#pragma unroll
        for (int t = 0; t < WMT; ++t) {
            int cA = wave * WMT + t;
            int rowA = (cA << 3) + srow;
            gload_lds16(A + (size_t)(m0 + rowA) * K + k0 + (gseg << 3), &sA[cA << 9]);
            if (t < 4) {
                int cB = (wave << 2) + t;
                int rowB = (cB << 3) + srow;
                gload_lds16(Bt + (size_t)(n0 + rowB) * K + k0 + (gseg << 3), &sB[cB << 9]);
            }
        }
        __syncthreads();
#pragma unroll
        for (int kk = 0; kk < 64; kk += 32) {
            int ks = (kk >> 3) + quad;
            short8 af[WMT], bf[4];
#pragma unroll
            for (int mt = 0; mt < WMT; ++mt) {
                int r = wm + (mt << 4) + l15;
                af[mt] = *(const short8*)&sA[(r << 6) + (((ks ^ swr) & 7) << 3)];
            }
#pragma unroll
            for (int nt = 0; nt < 4; ++nt) {
                int r = wn + (nt << 4) + l15;
                bf[nt] = *(const short8*)&sB[(r << 6) + (((ks ^ swr) & 7) << 3)];
            }
#pragma unroll
            for (int mt = 0; mt < WMT; ++mt)
#pragma unroll
                for (int nt = 0; nt < 4; ++nt)
                    acc[mt][nt] = mfma16(af[mt], bf[nt], acc[mt][nt]);
        }
        __syncthreads();
    }

    if (MODE == 0 && n0 >= 2048) {
        // --- V region: fused transpose+permute into Vt ---
#pragma unroll
        for (int mt = 0; mt < WMT; ++mt)
#pragma unroll
            for (int nt = 0; nt < 4; ++nt)
#pragma unroll
                for (int r = 0; r < 4; ++r) {
                    int row = m0 + wm + (mt << 4) + (quad << 2) + r;
                    int col = n0 + wn + (nt << 4) + l15;
                    float v = acc[mt][nt][r] + bkv[col - 1024];
                    int bb = row >> 10, k = row & 1023;
                    int h = (col - 2048) >> 6, d = col & 63;
                    int kt = k >> 6, kin = k & 63;
                    int kp = ((kin & 15) << 2) | (kin >> 4);
                    Vt[(size_t)((((bb << 4) + h) << 6) + d) * 1024
                       + (kt << 6) + kp] = f2bf(v);
                }
        return;
    }

#pragma unroll
    for (int mt = 0; mt < WMT; ++mt)
#pragma unroll
        for (int nt = 0; nt < 4; ++nt)
#pragma unroll
            for (int r = 0; r < 4; ++r) {
                int row = m0 + wm + (mt << 4) + (quad << 2) + r;
                int col = n0 + wn + (nt << 4) + l15;
                if (MODE == 1) {
                    float v = acc[mt][nt][r] + bq[col];
                    size_t idx = (size_t)row * N + col;
                    Cf[idx] = v + bf2f(resb[idx]);
                } else {
                    float bias = (col < 1024) ? bq[col] : bkv[col - 1024];
                    float v = acc[mt][nt][r] + bias;
                    if (col < 1024) v *= qscale;
                    Cb[(size_t)row * N + col] = f2bf(v);
                }
            }
}

// ---------------------------------------------------------------------------
// Flash attention, no-max softmax (scores bounded; scale+log2e folded into Q
// by the projection epilogue).  QKVp: [8192][3072] bf16, Q cols 0..1023
// (pre-scaled), K cols 1024..2047.  Vt: [bh*64+d][k'] (key-permuted).
// Block: 4 waves x 32 q-rows = 128-row strip; each block does strips j, 7-j.
// ---------------------------------------------------------------------------
__global__ __launch_bounds__(256) void attn_kernel(
    const u16* __restrict__ QKVp, const u16* __restrict__ Vt,
    const int* __restrict__ lens, u16* __restrict__ O) {
    int bh = blockIdx.x;
    int b = bh >> 4, h = bh & 15;
    int j = blockIdx.y;          // strip pair: j and 7-j
    int len = lens[b];
    int cap = (len - 1) >> 6;    // last key tile with any valid key
    int tid = threadIdx.x, lane = tid & 63, w = tid >> 6;
    int quad = lane >> 4, l15 = lane & 15;

    __shared__ __align__(16) u16 sK[64 * 64];   // [key][d], seg-swizzled
    __shared__ __align__(16) u16 sV[64 * 64];   // [d][k'],  seg-swizzled
    __shared__ __align__(16) u16 sP[4 * 2048];  // per-wave 32x64 bf16 P
    u16* sPw = &sP[w << 11];

    int lrow = lane >> 3;       // 0..7: row within an 8-row staging chunk
    int lseg = lane & 7;

    fx4 zero = {0.0f, 0.0f, 0.0f, 0.0f};

#pragma unroll
    for (int phase = 0; phase < 2; ++phase) {
        int s = phase ? (7 - j) : j;
        int q0 = s << 7;
        int wq0 = q0 + (w << 5);
        int ktend_blk = min((q0 + 127) >> 6, cap);
        int ktend_w   = min((wq0 + 31) >> 6, cap);

        // Q fragments in registers for the whole strip
        short8 qf[2][2];
#pragma unroll
        for (int mt = 0; mt < 2; ++mt)
#pragma unroll
            for (int kk = 0; kk < 2; ++kk) {
                int qrow = (b << 10) + wq0 + (mt << 4) + l15;
                qf[mt][kk] = *(const short8*)(QKVp + (size_t)qrow * 3072
                              + (h << 6) + (kk << 5) + (quad << 3));
            }

        fx4 oacc[2][4];
        float lsum[2][4];
#pragma unroll
        for (int mt = 0; mt < 2; ++mt)
#pragma unroll
            for (int nt = 0; nt < 4; ++nt) oacc[mt][nt] = zero;
#pragma unroll
        for (int mt = 0; mt < 2; ++mt)
#pragma unroll
            for (int r = 0; r < 4; ++r) lsum[mt][r] = 0.0f;

        for (int kt = 0; kt <= ktend_blk; ++kt) {
            int k0g = kt << 6;
            // --- stage K and Vt tiles (async, direct-to-LDS) ---
#pragma unroll
            for (int i = 0; i < 2; ++i) {
                int row = (w << 4) + (i << 3) + lrow;      // key row / d row
                int gs = lseg ^ (row & 7);
                gload_lds16(QKVp + (size_t)((b << 10) + k0g + row) * 3072
                               + 1024 + (h << 6) + (gs << 3),
                            &sK[((w << 1) + i) << 9]);
                gload_lds16(Vt + (size_t)((bh << 6) + row) * 1024
                               + k0g + (gs << 3),
                            &sV[((w << 1) + i) << 9]);
            }
            __syncthreads();   // drains vmcnt -> staged data visible

            if (kt <= ktend_w) {
                // --- S = Q K^T ---
                fx4 sacc[2][4];
#pragma unroll
                for (int mt = 0; mt < 2; ++mt)
#pragma unroll
                    for (int nt = 0; nt < 4; ++nt) sacc[mt][nt] = zero;
#pragma unroll
                for (int kk = 0; kk < 2; ++kk) {
                    int seg = (kk << 2) + quad;
                    short8 kf[4];
#pragma unroll
                    for (int nt = 0; nt < 4; ++nt) {
                        int row = (nt << 4) + l15;
                        kf[nt] = *(const short8*)&sK[(row << 6)
                                   + (((seg ^ (row & 7)) & 7) << 3)];
                    }
#pragma unroll
                    for (int mt = 0; mt < 2; ++mt)
#pragma unroll
                        for (int nt = 0; nt < 4; ++nt)
                            sacc[mt][nt] = mfma16(qf[mt][kk], kf[nt], sacc[mt][nt]);
                }

                // --- masks (boundary tiles only) ---
                bool needm = ((k0g + 63) > wq0) || ((k0g + 64) > len);
                if (needm) {
#pragma unroll
                    for (int mt = 0; mt < 2; ++mt)
#pragma unroll
                        for (int nt = 0; nt < 4; ++nt) {
                            int kg = k0g + (nt << 4) + l15;
#pragma unroll
                            for (int r = 0; r < 4; ++r) {
                                int qr = wq0 + (mt << 4) + (quad << 2) + r;
                                if (kg > qr || kg >= len)
                                    sacc[mt][nt][r] = -30000.0f;
                            }
                        }
                }

                // --- p = exp2(s), accumulate l, pack P to LDS ---
#pragma unroll
                for (int mt = 0; mt < 2; ++mt) {
#pragma unroll
                    for (int nt = 0; nt < 4; ++nt)
#pragma unroll
                        for (int r = 0; r < 4; ++r)
                            sacc[mt][nt][r] = fast_exp2(sacc[mt][nt][r]);
#pragma unroll
                    for (int r = 0; r < 4; ++r) {
                        lsum[mt][r] += (sacc[mt][0][r] + sacc[mt][1][r])
                                     + (sacc[mt][2][r] + sacc[mt][3][r]);
                        int row = (mt << 4) + (quad << 2) + r;
                        u32 lo = pack_bf2(sacc[mt][0][r], sacc[mt][1][r]);
                        u32 hi = pack_bf2(sacc[mt][2][r], sacc[mt][3][r]);
                        uint2 pv; pv.x = lo; pv.y = hi;
                        int addr = (row << 6)
                                 + (((((l15 >> 1)) ^ (row & 7)) & 7) << 3)
                                 + ((l15 & 1) << 2);
                        *(uint2*)&sPw[addr] = pv;
                    }
                }
                // sP is wave-private -> only need LDS-op completion, no barrier
                __builtin_amdgcn_s_waitcnt(0xC07F);  // lgkmcnt(0)

                // --- O += P V ---
#pragma unroll
                for (int kk = 0; kk < 2; ++kk) {
                    int seg = (kk << 2) + quad;
                    short8 vf[4], pf[2];
#pragma unroll
                    for (int nt = 0; nt < 4; ++nt) {
                        int row = (nt << 4) + l15;
                        vf[nt] = *(const short8*)&sV[(row << 6)
                                   + (((seg ^ (row & 7)) & 7) << 3)];
                    }
#pragma unroll
                    for (int mt = 0; mt < 2; ++mt) {
                        int row = (mt << 4) + l15;
                        pf[mt] = *(const short8*)&sPw[(row << 6)
                                   + (((seg ^ (row & 7)) & 7) << 3)];
                    }
#pragma unroll
                    for (int mt = 0; mt < 2; ++mt)
#pragma unroll
                        for (int nt = 0; nt < 4; ++nt)
                            oacc[mt][nt] = mfma16(pf[mt], vf[nt], oacc[mt][nt]);
                }
            }
            __syncthreads();   // protect sK/sV for next tile's staging
        }

        // --- reduce l across the 16 lanes of each quad, normalize, write ---
#pragma unroll
        for (int mt = 0; mt < 2; ++mt)
#pragma unroll
            for (int r = 0; r < 4; ++r) {
                float v = lsum[mt][r];
                v += __shfl_xor(v, 1, 64);
                v += __shfl_xor(v, 2, 64);
                v += __shfl_xor(v, 4, 64);
                v += __shfl_xor(v, 8, 64);
                lsum[mt][r] = __builtin_amdgcn_rcpf(v);
            }
#pragma unroll
        for (int mt = 0; mt < 2; ++mt)
#pragma unroll
            for (int nt = 0; nt < 4; ++nt)
#pragma unroll
                for (int r = 0; r < 4; ++r) {
                    int row = (b << 10) + wq0 + (mt << 4) + (quad << 2) + r;
                    int col = (h << 6) + (nt << 4) + l15;
                    O[((size_t)row << 10) + col] =
                        f2bf(oacc[mt][nt][r] * lsum[mt][r]);
                }
    }
}

// ---------------------------------------------------------------------------
extern "C" void kernel_launch(void* const* d_in, const int* in_sizes, int n_in,
                              void* d_out, int out_size, void* d_ws, size_t ws_size,
                              hipStream_t stream) {
    (void)in_sizes; (void)n_in; (void)out_size; (void)ws_size;
    const float* x    = (const float*)d_in[0];
    const int*   lens = (const int*)d_in[2];
    const float* Wq   = (const float*)d_in[3];
    const float* bq   = (const float*)d_in[4];
    const float* Wkv  = (const float*)d_in[5];
    const float* bkv  = (const float*)d_in[6];
    const float* Wo   = (const float*)d_in[7];
    const float* bo   = (const float*)d_in[8];
    const float* gam  = (const float*)d_in[9];
    const float* bet  = (const float*)d_in[10];
    float* out = (float*)d_out;

    char* w = (char*)d_ws;
    u16* xln_b  = (u16*)w;  w += (size_t)8192 * 1024 * 2;   // 16 MB: LN out (GEMM A + bf16 residual)
    u16* Wall_t = (u16*)w;  w += (size_t)4096 * 1024 * 2;   //  8 MB: [Wq^T | Wkv^T | Wo^T]
    u16* QKVp   = (u16*)w;  w += (size_t)8192 * 3072 * 2;   // 48 MB: Q(scaled)|K (V cols unused)
    u16* Vt     = (u16*)w;  w += (size_t)8192 * 1024 * 2;   // 16 MB: V transposed + key-permuted
    u16* AO     = (u16*)w;  w += (size_t)8192 * 1024 * 2;   // 16 MB: attention out
    // total 104 MB

    ln_wt_kernel<<<6144, 256, 0, stream>>>(x, gam, bet, xln_b, Wq, Wkv, Wo, Wall_t);
    gemm_qkv8<<<384, 512, 0, stream>>>(xln_b, Wall_t, bq, bkv, QKVp, Vt,
                                       0.125f * LOG2E);
    attn_kernel<<<dim3(128, 4), 256, 0, stream>>>(QKVp, Vt, lens, AO);
    gemm_bt<1, 4><<<dim3(8, 64), 256, 0, stream>>>(AO, Wall_t + (size_t)3072 * 1024,
        bo, nullptr, xln_b, out, nullptr, nullptr, 8192, 1024, 1024, 1.0f);
}

// Round 5
// 262.057 us; speedup vs baseline: 1.1336x; 1.1336x over previous
//
#include <hip/hip_runtime.h>

typedef unsigned short u16;
typedef unsigned int u32;
typedef __attribute__((ext_vector_type(8))) short short8;
typedef __attribute__((ext_vector_type(4))) float fx4;

#define LOG2E 1.44269504088896340736f

__device__ __forceinline__ u16 f2bf(float f) {
    unsigned int u = __float_as_uint(f);
    u += 0x7fffu + ((u >> 16) & 1u);
    return (u16)(u >> 16);
}

__device__ __forceinline__ float bf2f(u16 v) {
    u32 u = ((u32)v) << 16;
    return __uint_as_float(u);
}

// pack two fp32 -> two truncated bf16 in one u32 (v_perm_b32)
__device__ __forceinline__ u32 pack_bf2(float lo, float hi) {
    return __builtin_amdgcn_perm(__float_as_uint(hi), __float_as_uint(lo), 0x07060302u);
}

__device__ __forceinline__ float fast_exp2(float x) {
#if __has_builtin(__builtin_amdgcn_exp2f)
    return __builtin_amdgcn_exp2f(x);
#else
    return exp2f(x);
#endif
}

__device__ __forceinline__ fx4 mfma16(short8 a, short8 b, fx4 c) {
    return __builtin_amdgcn_mfma_f32_16x16x32_bf16(a, b, c, 0, 0, 0);
}

__device__ __forceinline__ void gload_lds16(const u16* g, u16* l) {
    __builtin_amdgcn_global_load_lds(
        (const __attribute__((address_space(1))) void*)g,
        (__attribute__((address_space(3))) void*)l, 16, 0, 0);
}

// ---------------------------------------------------------------------------
// Fused LayerNorm + weight transpose (heterogeneous grid, 6144 blocks):
//   blocks 0..2047:   LN, 4 rows each (one wave per row, shuffle-only).
//   blocks 2048..6143: 32x32 transpose tiles of [Wq|Wkv|Wo] -> Wall_t.
// ---------------------------------------------------------------------------
__global__ __launch_bounds__(256) void ln_wt_kernel(
    const float* __restrict__ x, const float* __restrict__ gamma,
    const float* __restrict__ beta, u16* __restrict__ yb,
    const float* __restrict__ Wq, const float* __restrict__ Wkv,
    const float* __restrict__ Wo, u16* __restrict__ Wt) {
    int blk = blockIdx.x;
    if (blk < 2048) {
        int wave = threadIdx.x >> 6, lane = threadIdx.x & 63;
        int row = (blk << 2) + wave;
        const float* xr = x + ((size_t)row << 10);
        float4 v[4];
        float s = 0.0f, sq = 0.0f;
#pragma unroll
        for (int i = 0; i < 4; ++i) {
            v[i] = *(const float4*)(xr + (i << 8) + (lane << 2));
            s  += v[i].x + v[i].y + v[i].z + v[i].w;
            sq += v[i].x * v[i].x + v[i].y * v[i].y + v[i].z * v[i].z + v[i].w * v[i].w;
        }
#pragma unroll
        for (int o = 32; o > 0; o >>= 1) {
            s  += __shfl_xor(s, o, 64);
            sq += __shfl_xor(sq, o, 64);
        }
        float mean = s * (1.0f / 1024.0f);
        float var  = sq * (1.0f / 1024.0f) - mean * mean;
        float rstd = rsqrtf(var + 1e-3f);
#pragma unroll
        for (int i = 0; i < 4; ++i) {
            int off = (i << 8) + (lane << 2);
            float4 g  = *(const float4*)(gamma + off);
            float4 bb = *(const float4*)(beta + off);
            float4 y;
            y.x = (v[i].x - mean) * rstd * g.x + bb.x;
            y.y = (v[i].y - mean) * rstd * g.y + bb.y;
            y.z = (v[i].z - mean) * rstd * g.z + bb.z;
            y.w = (v[i].w - mean) * rstd * g.w + bb.w;
            unsigned long long p = (unsigned long long)f2bf(y.x)
                | ((unsigned long long)f2bf(y.y) << 16)
                | ((unsigned long long)f2bf(y.z) << 32)
                | ((unsigned long long)f2bf(y.w) << 48);
            *(unsigned long long*)(yb + ((size_t)row << 10) + off) = p;
        }
    } else {
        int wtb = blk - 2048;
        int n0 = (wtb & 127) << 5;   // 0..4095
        int k0 = (wtb >> 7) << 5;    // 0..1023
        const float* W; int sn0, SN;
        if (n0 < 1024)      { W = Wq;  sn0 = n0;        SN = 1024; }
        else if (n0 < 3072) { W = Wkv; sn0 = n0 - 1024; SN = 2048; }
        else                { W = Wo;  sn0 = n0 - 3072; SN = 1024; }
        __shared__ float tile[32][33];
        int tx = threadIdx.x & 31, ty = threadIdx.x >> 5;  // ty 0..7
#pragma unroll
        for (int r = 0; r < 4; ++r)
            tile[ty + r * 8][tx] = W[(size_t)(k0 + ty + r * 8) * SN + sn0 + tx];
        __syncthreads();
#pragma unroll
        for (int r = 0; r < 4; ++r)
            Wt[(size_t)(n0 + ty + r * 8) * 1024 + k0 + tx] = f2bf(tile[tx][ty + r * 8]);
    }
}

// ---------------------------------------------------------------------------
// GEMM: C[M,N] = A[M,K] @ Bt[N,K]^T + bias.  128x128 block tile (WMT=4),
// 2x2 waves of 64x64, 16x16x32 mfma, BK=64, global_load_lds w16 staging,
// XOR-swizzled LDS (zero-conflict 16-row fragment reads).
// [NOTE: the 256x256 8-phase counted-vmcnt port (r1-r3) was NULL on this
//  problem -- 110-114us vs this kernel's 77us; MfmaUtil 18% vs 27%. At
//  1 block/CU its lockstep phases serialize LDS-read and MFMA; this
//  2-phase kernel's ~5 resident blocks/CU overlap them implicitly (m114).]
// MODE 0 (QKV proj): cols<1024 -> bf16 QKVp with bias bq, scale qscale;
//                    1024<=col<2048 -> bf16 QKVp with bias bkv (K part);
//                    col>=2048 -> V: written DIRECTLY to Vt transposed with
//                    the k' permutation (k' = 4*(k&15) + (k>>4)) - fused
//                    vtrans.  QKVp V-cols are never written.
// MODE 1 (O proj):   fp32 out + bias bq + bf16 residual.
// ---------------------------------------------------------------------------
template <int MODE, int WMT>
__global__ __launch_bounds__(256) void gemm_bt(
    const u16* __restrict__ A, const u16* __restrict__ Bt,
    const float* __restrict__ bq, const float* __restrict__ bkv,
    const u16* __restrict__ resb, float* __restrict__ Cf, u16* __restrict__ Cb,
    u16* __restrict__ Vt, int M, int N, int K, float qscale) {
    __shared__ __align__(16) u16 sA[WMT * 32 * 64];
    __shared__ __align__(16) u16 sB[128 * 64];
    int m0 = blockIdx.y * (WMT * 32), n0 = blockIdx.x << 7;
    int tid = threadIdx.x, lane = tid & 63, wave = tid >> 6;
    int quad = lane >> 4, l15 = lane & 15, swr = lane & 7;
    int wm = (wave >> 1) * (WMT * 16), wn = (wave & 1) << 6;
    int srow = lane >> 3;
    int gseg = (lane & 7) ^ srow;

    fx4 acc[WMT][4];
    fx4 zero = {0.0f, 0.0f, 0.0f, 0.0f};
#pragma unroll
    for (int i = 0; i < WMT; ++i)
#pragma unroll
        for (int j = 0; j < 4; ++j) acc[i][j] = zero;

    for (int k0 = 0; k0 < K; k0 += 64) {
#pragma unroll
        for (int t = 0; t < WMT; ++t) {
            int cA = wave * WMT + t;
            int rowA = (cA << 3) + srow;
            gload_lds16(A + (size_t)(m0 + rowA) * K + k0 + (gseg << 3), &sA[cA << 9]);
            if (t < 4) {
                int cB = (wave << 2) + t;
                int rowB = (cB << 3) + srow;
                gload_lds16(Bt + (size_t)(n0 + rowB) * K + k0 + (gseg << 3), &sB[cB << 9]);
            }
        }
        __syncthreads();
#pragma unroll
        for (int kk = 0; kk < 64; kk += 32) {
            int ks = (kk >> 3) + quad;
            short8 af[WMT], bf[4];
#pragma unroll
            for (int mt = 0; mt < WMT; ++mt) {
                int r = wm + (mt << 4) + l15;
                af[mt] = *(const short8*)&sA[(r << 6) + (((ks ^ swr) & 7) << 3)];
            }
#pragma unroll
            for (int nt = 0; nt < 4; ++nt) {
                int r = wn + (nt << 4) + l15;
                bf[nt] = *(const short8*)&sB[(r << 6) + (((ks ^ swr) & 7) << 3)];
            }
#pragma unroll
            for (int mt = 0; mt < WMT; ++mt)
#pragma unroll
                for (int nt = 0; nt < 4; ++nt)
                    acc[mt][nt] = mfma16(af[mt], bf[nt], acc[mt][nt]);
        }
        __syncthreads();
    }

    if (MODE == 0 && n0 >= 2048) {
        // --- V region: fused transpose+permute into Vt ---
#pragma unroll
        for (int mt = 0; mt < WMT; ++mt)
#pragma unroll
            for (int nt = 0; nt < 4; ++nt)
#pragma unroll
                for (int r = 0; r < 4; ++r) {
                    int row = m0 + wm + (mt << 4) + (quad << 2) + r;
                    int col = n0 + wn + (nt << 4) + l15;
                    float v = acc[mt][nt][r] + bkv[col - 1024];
                    int bb = row >> 10, k = row & 1023;
                    int h = (col - 2048) >> 6, d = col & 63;
                    int kt = k >> 6, kin = k & 63;
                    int kp = ((kin & 15) << 2) | (kin >> 4);
                    Vt[(size_t)((((bb << 4) + h) << 6) + d) * 1024
                       + (kt << 6) + kp] = f2bf(v);
                }
        return;
    }

#pragma unroll
    for (int mt = 0; mt < WMT; ++mt)
#pragma unroll
        for (int nt = 0; nt < 4; ++nt)
#pragma unroll
            for (int r = 0; r < 4; ++r) {
                int row = m0 + wm + (mt << 4) + (quad << 2) + r;
                int col = n0 + wn + (nt << 4) + l15;
                if (MODE == 1) {
                    float v = acc[mt][nt][r] + bq[col];
                    size_t idx = (size_t)row * N + col;
                    Cf[idx] = v + bf2f(resb[idx]);
                } else {
                    float bias = (col < 1024) ? bq[col] : bkv[col - 1024];
                    float v = acc[mt][nt][r] + bias;
                    if (col < 1024) v *= qscale;
                    Cb[(size_t)row * N + col] = f2bf(v);
                }
            }
}

// ---------------------------------------------------------------------------
// Flash attention, no-max softmax (scores bounded; scale+log2e folded into Q
// by the projection epilogue).  QKVp: [8192][3072] bf16, Q cols 0..1023
// (pre-scaled), K cols 1024..2047.  Vt: [bh*64+d][k'] (key-permuted).
// Block: 4 waves x 32 q-rows = 128-row strip; each block does strips j, 7-j.
// v4: K/V tiles DOUBLE-BUFFERED with prefetch-before-compute -- the stage
// for tile kt+1 is issued before computing tile kt, so the __syncthreads
// vmcnt(0) drain lands after ~1000cy of QK/softmax/PV has covered the HBM
// round-trip (previously: stage(kt) -> barrier = fully exposed latency per
// tile).  One barrier per tile does both WAR protection and visibility.
// ---------------------------------------------------------------------------
__global__ __launch_bounds__(256) void attn_kernel(
    const u16* __restrict__ QKVp, const u16* __restrict__ Vt,
    const int* __restrict__ lens, u16* __restrict__ O) {
    int bh = blockIdx.x;
    int b = bh >> 4, h = bh & 15;
    int j = blockIdx.y;          // strip pair: j and 7-j
    int len = lens[b];
    int cap = (len - 1) >> 6;    // last key tile with any valid key
    int tid = threadIdx.x, lane = tid & 63, w = tid >> 6;
    int quad = lane >> 4, l15 = lane & 15;

    __shared__ __align__(16) u16 sK[2][64 * 64];   // [key][d], seg-swizzled
    __shared__ __align__(16) u16 sV[2][64 * 64];   // [d][k'],  seg-swizzled
    __shared__ __align__(16) u16 sP[4 * 2048];     // per-wave 32x64 bf16 P
    u16* sPw = &sP[w << 11];

    int lrow = lane >> 3;       // 0..7: row within an 8-row staging chunk
    int lseg = lane & 7;

    // stage K and Vt tiles for key-tile kt into buffer buf (async LDS-DMA)
    auto stage = [&](int kt, int buf) {
        int k0g = kt << 6;
#pragma unroll
        for (int i = 0; i < 2; ++i) {
            int row = (w << 4) + (i << 3) + lrow;      // key row / d row
            int gs = lseg ^ (row & 7);
            gload_lds16(QKVp + (size_t)((b << 10) + k0g + row) * 3072
                           + 1024 + (h << 6) + (gs << 3),
                        &sK[buf][((w << 1) + i) << 9]);
            gload_lds16(Vt + (size_t)((bh << 6) + row) * 1024
                           + k0g + (gs << 3),
                        &sV[buf][((w << 1) + i) << 9]);
        }
    };

    fx4 zero = {0.0f, 0.0f, 0.0f, 0.0f};

#pragma unroll
    for (int phase = 0; phase < 2; ++phase) {
        int s = phase ? (7 - j) : j;
        int q0 = s << 7;
        int wq0 = q0 + (w << 5);
        int ktend_blk = min((q0 + 127) >> 6, cap);
        int ktend_w   = min((wq0 + 31) >> 6, cap);

        // Q fragments in registers for the whole strip
        short8 qf[2][2];
#pragma unroll
        for (int mt = 0; mt < 2; ++mt)
#pragma unroll
            for (int kk = 0; kk < 2; ++kk) {
                int qrow = (b << 10) + wq0 + (mt << 4) + l15;
                qf[mt][kk] = *(const short8*)(QKVp + (size_t)qrow * 3072
                              + (h << 6) + (kk << 5) + (quad << 3));
            }

        fx4 oacc[2][4];
        float lsum[2][4];
#pragma unroll
        for (int mt = 0; mt < 2; ++mt)
#pragma unroll
            for (int nt = 0; nt < 4; ++nt) oacc[mt][nt] = zero;
#pragma unroll
        for (int mt = 0; mt < 2; ++mt)
#pragma unroll
            for (int r = 0; r < 4; ++r) lsum[mt][r] = 0.0f;

        // prologue: tile 0 into buf 0, drain, visible to all
        stage(0, 0);
        __syncthreads();

        for (int kt = 0; kt <= ktend_blk; ++kt) {
            int cb = kt & 1;
            // prefetch next tile into the other buffer (hidden under compute)
            if (kt < ktend_blk) stage(kt + 1, cb ^ 1);

            if (kt <= ktend_w) {
                int k0g = kt << 6;
                // --- S = Q K^T ---
                fx4 sacc[2][4];
#pragma unroll
                for (int mt = 0; mt < 2; ++mt)
#pragma unroll
                    for (int nt = 0; nt < 4; ++nt) sacc[mt][nt] = zero;
#pragma unroll
                for (int kk = 0; kk < 2; ++kk) {
                    int seg = (kk << 2) + quad;
                    short8 kf[4];
#pragma unroll
                    for (int nt = 0; nt < 4; ++nt) {
                        int row = (nt << 4) + l15;
                        kf[nt] = *(const short8*)&sK[cb][(row << 6)
                                   + (((seg ^ (row & 7)) & 7) << 3)];
                    }
#pragma unroll
                    for (int mt = 0; mt < 2; ++mt)
#pragma unroll
                        for (int nt = 0; nt < 4; ++nt)
                            sacc[mt][nt] = mfma16(qf[mt][kk], kf[nt], sacc[mt][nt]);
                }

                // --- masks (boundary tiles only) ---
                bool needm = ((k0g + 63) > wq0) || ((k0g + 64) > len);
                if (needm) {
#pragma unroll
                    for (int mt = 0; mt < 2; ++mt)
#pragma unroll
                        for (int nt = 0; nt < 4; ++nt) {
                            int kg = k0g + (nt << 4) + l15;
#pragma unroll
                            for (int r = 0; r < 4; ++r) {
                                int qr = wq0 + (mt << 4) + (quad << 2) + r;
                                if (kg > qr || kg >= len)
                                    sacc[mt][nt][r] = -30000.0f;
                            }
                        }
                }

                // --- p = exp2(s), accumulate l, pack P to LDS ---
#pragma unroll
                for (int mt = 0; mt < 2; ++mt) {
#pragma unroll
                    for (int nt = 0; nt < 4; ++nt)
#pragma unroll
                        for (int r = 0; r < 4; ++r)
                            sacc[mt][nt][r] = fast_exp2(sacc[mt][nt][r]);
#pragma unroll
                    for (int r = 0; r < 4; ++r) {
                        lsum[mt][r] += (sacc[mt][0][r] + sacc[mt][1][r])
                                     + (sacc[mt][2][r] + sacc[mt][3][r]);
                        int row = (mt << 4) + (quad << 2) + r;
                        u32 lo = pack_bf2(sacc[mt][0][r], sacc[mt][1][r]);
                        u32 hi = pack_bf2(sacc[mt][2][r], sacc[mt][3][r]);
                        uint2 pv; pv.x = lo; pv.y = hi;
                        int addr = (row << 6)
                                 + (((((l15 >> 1)) ^ (row & 7)) & 7) << 3)
                                 + ((l15 & 1) << 2);
                        *(uint2*)&sPw[addr] = pv;
                    }
                }
                // sP is wave-private -> only need LDS-op completion, no barrier
                __builtin_amdgcn_s_waitcnt(0xC07F);  // lgkmcnt(0)

                // --- O += P V ---
#pragma unroll
                for (int kk = 0; kk < 2; ++kk) {
                    int seg = (kk << 2) + quad;
                    short8 vf[4], pf[2];
#pragma unroll
                    for (int nt = 0; nt < 4; ++nt) {
                        int row = (nt << 4) + l15;
                        vf[nt] = *(const short8*)&sV[cb][(row << 6)
                                   + (((seg ^ (row & 7)) & 7) << 3)];
                    }
#pragma unroll
                    for (int mt = 0; mt < 2; ++mt) {
                        int row = (mt << 4) + l15;
                        pf[mt] = *(const short8*)&sPw[(row << 6)
                                   + (((seg ^ (row & 7)) & 7) << 3)];
                    }
#pragma unroll
                    for (int mt = 0; mt < 2; ++mt)
#pragma unroll
                        for (int nt = 0; nt < 4; ++nt)
                            oacc[mt][nt] = mfma16(pf[mt], vf[nt], oacc[mt][nt]);
                }
            }
            // one barrier per tile: (a) all readers of buf cb are done before
            // it is re-staged at kt+2; (b) drains the kt+1 prefetch (vmcnt 0)
            // after it had the whole compute phase to fly.
            __syncthreads();
        }

        // --- reduce l across the 16 lanes of each quad, normalize, write ---
#pragma unroll
        for (int mt = 0; mt < 2; ++mt)
#pragma unroll
            for (int r = 0; r < 4; ++r) {
                float v = lsum[mt][r];
                v += __shfl_xor(v, 1, 64);
                v += __shfl_xor(v, 2, 64);
                v += __shfl_xor(v, 4, 64);
                v += __shfl_xor(v, 8, 64);
                lsum[mt][r] = __builtin_amdgcn_rcpf(v);
            }
#pragma unroll
        for (int mt = 0; mt < 2; ++mt)
#pragma unroll
            for (int nt = 0; nt < 4; ++nt)
#pragma unroll
                for (int r = 0; r < 4; ++r) {
                    int row = (b << 10) + wq0 + (mt << 4) + (quad << 2) + r;
                    int col = (h << 6) + (nt << 4) + l15;
                    O[((size_t)row << 10) + col] =
                        f2bf(oacc[mt][nt][r] * lsum[mt][r]);
                }
    }
}

// ---------------------------------------------------------------------------
extern "C" void kernel_launch(void* const* d_in, const int* in_sizes, int n_in,
                              void* d_out, int out_size, void* d_ws, size_t ws_size,
                              hipStream_t stream) {
    (void)in_sizes; (void)n_in; (void)out_size; (void)ws_size;
    const float* x    = (const float*)d_in[0];
    const int*   lens = (const int*)d_in[2];
    const float* Wq   = (const float*)d_in[3];
    const float* bq   = (const float*)d_in[4];
    const float* Wkv  = (const float*)d_in[5];
    const float* bkv  = (const float*)d_in[6];
    const float* Wo   = (const float*)d_in[7];
    const float* bo   = (const float*)d_in[8];
    const float* gam  = (const float*)d_in[9];
    const float* bet  = (const float*)d_in[10];
    float* out = (float*)d_out;

    char* w = (char*)d_ws;
    u16* xln_b  = (u16*)w;  w += (size_t)8192 * 1024 * 2;   // 16 MB: LN out (GEMM A + bf16 residual)
    u16* Wall_t = (u16*)w;  w += (size_t)4096 * 1024 * 2;   //  8 MB: [Wq^T | Wkv^T | Wo^T]
    u16* QKVp   = (u16*)w;  w += (size_t)8192 * 3072 * 2;   // 48 MB: Q(scaled)|K (V cols unused)
    u16* Vt     = (u16*)w;  w += (size_t)8192 * 1024 * 2;   // 16 MB: V transposed + key-permuted
    u16* AO     = (u16*)w;  w += (size_t)8192 * 1024 * 2;   // 16 MB: attention out
    // total 104 MB

    ln_wt_kernel<<<6144, 256, 0, stream>>>(x, gam, bet, xln_b, Wq, Wkv, Wo, Wall_t);
    gemm_bt<0, 4><<<dim3(24, 64), 256, 0, stream>>>(xln_b, Wall_t, bq, bkv,
        nullptr, nullptr, QKVp, Vt, 8192, 3072, 1024, 0.125f * LOG2E);
    attn_kernel<<<dim3(128, 4), 256, 0, stream>>>(QKVp, Vt, lens, AO);
    gemm_bt<1, 4><<<dim3(8, 64), 256, 0, stream>>>(AO, Wall_t + (size_t)3072 * 1024,
        bo, nullptr, xln_b, out, nullptr, nullptr, 8192, 1024, 1024, 1.0f);
}

// Round 6
// 260.299 us; speedup vs baseline: 1.1413x; 1.0068x over previous
//
#include <hip/hip_runtime.h>

typedef unsigned short u16;
typedef unsigned int u32;
typedef __attribute__((ext_vector_type(8))) short short8;
typedef __attribute__((ext_vector_type(4))) float fx4;

#define LOG2E 1.44269504088896340736f

__device__ __forceinline__ u16 f2bf(float f) {
    unsigned int u = __float_as_uint(f);
    u += 0x7fffu + ((u >> 16) & 1u);
    return (u16)(u >> 16);
}

__device__ __forceinline__ float bf2f(u16 v) {
    u32 u = ((u32)v) << 16;
    return __uint_as_float(u);
}

// pack two fp32 -> two truncated bf16 in one u32 (v_perm_b32)
__device__ __forceinline__ u32 pack_bf2(float lo, float hi) {
    return __builtin_amdgcn_perm(__float_as_uint(hi), __float_as_uint(lo), 0x07060302u);
}

__device__ __forceinline__ float fast_exp2(float x) {
#if __has_builtin(__builtin_amdgcn_exp2f)
    return __builtin_amdgcn_exp2f(x);
#else
    return exp2f(x);
#endif
}

__device__ __forceinline__ fx4 mfma16(short8 a, short8 b, fx4 c) {
    return __builtin_amdgcn_mfma_f32_16x16x32_bf16(a, b, c, 0, 0, 0);
}

__device__ __forceinline__ void gload_lds16(const u16* g, u16* l) {
    __builtin_amdgcn_global_load_lds(
        (const __attribute__((address_space(1))) void*)g,
        (__attribute__((address_space(3))) void*)l, 16, 0, 0);
}

// ---------------------------------------------------------------------------
// Fused LayerNorm + weight transpose (heterogeneous grid, 6144 blocks):
//   blocks 0..2047:   LN, 4 rows each (one wave per row, shuffle-only).
//   blocks 2048..6143: 32x32 transpose tiles of [Wq|Wkv|Wo] -> Wall_t.
// ---------------------------------------------------------------------------
__global__ __launch_bounds__(256) void ln_wt_kernel(
    const float* __restrict__ x, const float* __restrict__ gamma,
    const float* __restrict__ beta, u16* __restrict__ yb,
    const float* __restrict__ Wq, const float* __restrict__ Wkv,
    const float* __restrict__ Wo, u16* __restrict__ Wt) {
    int blk = blockIdx.x;
    if (blk < 2048) {
        int wave = threadIdx.x >> 6, lane = threadIdx.x & 63;
        int row = (blk << 2) + wave;
        const float* xr = x + ((size_t)row << 10);
        float4 v[4];
        float s = 0.0f, sq = 0.0f;
#pragma unroll
        for (int i = 0; i < 4; ++i) {
            v[i] = *(const float4*)(xr + (i << 8) + (lane << 2));
            s  += v[i].x + v[i].y + v[i].z + v[i].w;
            sq += v[i].x * v[i].x + v[i].y * v[i].y + v[i].z * v[i].z + v[i].w * v[i].w;
        }
#pragma unroll
        for (int o = 32; o > 0; o >>= 1) {
            s  += __shfl_xor(s, o, 64);
            sq += __shfl_xor(sq, o, 64);
        }
        float mean = s * (1.0f / 1024.0f);
        float var  = sq * (1.0f / 1024.0f) - mean * mean;
        float rstd = rsqrtf(var + 1e-3f);
#pragma unroll
        for (int i = 0; i < 4; ++i) {
            int off = (i << 8) + (lane << 2);
            float4 g  = *(const float4*)(gamma + off);
            float4 bb = *(const float4*)(beta + off);
            float4 y;
            y.x = (v[i].x - mean) * rstd * g.x + bb.x;
            y.y = (v[i].y - mean) * rstd * g.y + bb.y;
            y.z = (v[i].z - mean) * rstd * g.z + bb.z;
            y.w = (v[i].w - mean) * rstd * g.w + bb.w;
            unsigned long long p = (unsigned long long)f2bf(y.x)
                | ((unsigned long long)f2bf(y.y) << 16)
                | ((unsigned long long)f2bf(y.z) << 32)
                | ((unsigned long long)f2bf(y.w) << 48);
            *(unsigned long long*)(yb + ((size_t)row << 10) + off) = p;
        }
    } else {
        int wtb = blk - 2048;
        int n0 = (wtb & 127) << 5;   // 0..4095
        int k0 = (wtb >> 7) << 5;    // 0..1023
        const float* W; int sn0, SN;
        if (n0 < 1024)      { W = Wq;  sn0 = n0;        SN = 1024; }
        else if (n0 < 3072) { W = Wkv; sn0 = n0 - 1024; SN = 2048; }
        else                { W = Wo;  sn0 = n0 - 3072; SN = 1024; }
        __shared__ float tile[32][33];
        int tx = threadIdx.x & 31, ty = threadIdx.x >> 5;  // ty 0..7
#pragma unroll
        for (int r = 0; r < 4; ++r)
            tile[ty + r * 8][tx] = W[(size_t)(k0 + ty + r * 8) * SN + sn0 + tx];
        __syncthreads();
#pragma unroll
        for (int r = 0; r < 4; ++r)
            Wt[(size_t)(n0 + ty + r * 8) * 1024 + k0 + tx] = f2bf(tile[tx][ty + r * 8]);
    }
}

// ---------------------------------------------------------------------------
// GEMM: C[M,N] = A[M,K] @ Bt[N,K]^T + bias.  128x128 block tile (WMT=4),
// 2x2 waves of 64x64, 16x16x32 mfma, BK=64, global_load_lds w16 staging,
// XOR-swizzled LDS (zero-conflict 16-row fragment reads).
// [NOTE: the 256x256 8-phase counted-vmcnt port (r1-r3) was NULL on this
//  problem -- 110-114us vs this kernel's 77us; MfmaUtil 18% vs 27%. At
//  1 block/CU its lockstep phases serialize LDS-read and MFMA; this
//  2-phase kernel's ~5 resident blocks/CU overlap them implicitly (m114).]
// v6: (T1) XCD-aware bijective block swizzle -- HW round-robins linear id
//  across 8 XCDs; remap so each XCD owns 8 contiguous m-rows x all n-tiles
//  (A panels 2MB -> L2-resident per XCD; was: 24 A-panel sharers spread over
//  8 XCDs, FETCH 77MB vs 24MB ideal).  Plus staging-address strength
//  reduction (per-thread src pointers += 64/step; LDS dests k-invariant).
// MODE 0 (QKV proj): cols<1024 -> bf16 QKVp with bias bq, scale qscale;
//                    1024<=col<2048 -> bf16 QKVp with bias bkv (K part);
//                    col>=2048 -> V: written DIRECTLY to Vt transposed with
//                    the k' permutation (k' = 4*(k&15) + (k>>4)) - fused
//                    vtrans.  QKVp V-cols are never written.
// MODE 1 (O proj):   fp32 out + bias bq + bf16 residual.
// ---------------------------------------------------------------------------
template <int MODE, int WMT>
__global__ __launch_bounds__(256) void gemm_bt(
    const u16* __restrict__ A, const u16* __restrict__ Bt,
    const float* __restrict__ bq, const float* __restrict__ bkv,
    const u16* __restrict__ resb, float* __restrict__ Cf, u16* __restrict__ Cb,
    u16* __restrict__ Vt, int M, int N, int K, float qscale) {
    __shared__ __align__(16) u16 sA[WMT * 32 * 64];
    __shared__ __align__(16) u16 sB[128 * 64];

    // T1 XCD swizzle (bijective, requires total%8==0: 1536 / 512 both ok)
    int nx = gridDim.x;
    int total = nx * gridDim.y;
    int id0 = blockIdx.x + blockIdx.y * nx;          // x-fastest linear id
    int nid = (id0 & 7) * (total >> 3) + (id0 >> 3); // XCD-contiguous remap
    int bx = nid % nx, by = nid / nx;
    int m0 = by * (WMT * 32), n0 = bx << 7;

    int tid = threadIdx.x, lane = tid & 63, wave = tid >> 6;
    int quad = lane >> 4, l15 = lane & 15, swr = lane & 7;
    int wm = (wave >> 1) * (WMT * 16), wn = (wave & 1) << 6;
    int srow = lane >> 3;
    int gseg = (lane & 7) ^ srow;

    fx4 acc[WMT][4];
    fx4 zero = {0.0f, 0.0f, 0.0f, 0.0f};
#pragma unroll
    for (int i = 0; i < WMT; ++i)
#pragma unroll
        for (int j = 0; j < 4; ++j) acc[i][j] = zero;

    // hoisted staging addresses (src advances by 64 elems per K-step)
    const u16* aSrc[WMT];
    const u16* bSrc[4];
    u16* aDst[WMT];
    u16* bDst[4];
#pragma unroll
    for (int t = 0; t < WMT; ++t) {
        int cA = wave * WMT + t;
        int rowA = (cA << 3) + srow;
        aSrc[t] = A + (size_t)(m0 + rowA) * K + (gseg << 3);
        aDst[t] = &sA[cA << 9];
    }
#pragma unroll
    for (int t = 0; t < 4; ++t) {
        int cB = (wave << 2) + t;
        int rowB = (cB << 3) + srow;
        bSrc[t] = Bt + (size_t)(n0 + rowB) * K + (gseg << 3);
        bDst[t] = &sB[cB << 9];
    }

    for (int k0 = 0; k0 < K; k0 += 64) {
#pragma unroll
        for (int t = 0; t < WMT; ++t) {
            gload_lds16(aSrc[t], aDst[t]);
            aSrc[t] += 64;
            if (t < 4) {
                gload_lds16(bSrc[t], bDst[t]);
                bSrc[t] += 64;
            }
        }
        __syncthreads();
#pragma unroll
        for (int kk = 0; kk < 64; kk += 32) {
            int ks = (kk >> 3) + quad;
            short8 af[WMT], bf[4];
#pragma unroll
            for (int mt = 0; mt < WMT; ++mt) {
                int r = wm + (mt << 4) + l15;
                af[mt] = *(const short8*)&sA[(r << 6) + (((ks ^ swr) & 7) << 3)];
            }
#pragma unroll
            for (int nt = 0; nt < 4; ++nt) {
                int r = wn + (nt << 4) + l15;
                bf[nt] = *(const short8*)&sB[(r << 6) + (((ks ^ swr) & 7) << 3)];
            }
#pragma unroll
            for (int mt = 0; mt < WMT; ++mt)
#pragma unroll
                for (int nt = 0; nt < 4; ++nt)
                    acc[mt][nt] = mfma16(af[mt], bf[nt], acc[mt][nt]);
        }
        __syncthreads();
    }

    if (MODE == 0 && n0 >= 2048) {
        // --- V region: fused transpose+permute into Vt ---
#pragma unroll
        for (int mt = 0; mt < WMT; ++mt)
#pragma unroll
            for (int nt = 0; nt < 4; ++nt)
#pragma unroll
                for (int r = 0; r < 4; ++r) {
                    int row = m0 + wm + (mt << 4) + (quad << 2) + r;
                    int col = n0 + wn + (nt << 4) + l15;
                    float v = acc[mt][nt][r] + bkv[col - 1024];
                    int bb = row >> 10, k = row & 1023;
                    int h = (col - 2048) >> 6, d = col & 63;
                    int kt = k >> 6, kin = k & 63;
                    int kp = ((kin & 15) << 2) | (kin >> 4);
                    Vt[(size_t)((((bb << 4) + h) << 6) + d) * 1024
                       + (kt << 6) + kp] = f2bf(v);
                }
        return;
    }

#pragma unroll
    for (int mt = 0; mt < WMT; ++mt)
#pragma unroll
        for (int nt = 0; nt < 4; ++nt)
#pragma unroll
            for (int r = 0; r < 4; ++r) {
                int row = m0 + wm + (mt << 4) + (quad << 2) + r;
                int col = n0 + wn + (nt << 4) + l15;
                if (MODE == 1) {
                    float v = acc[mt][nt][r] + bq[col];
                    size_t idx = (size_t)row * N + col;
                    Cf[idx] = v + bf2f(resb[idx]);
                } else {
                    float bias = (col < 1024) ? bq[col] : bkv[col - 1024];
                    float v = acc[mt][nt][r] + bias;
                    if (col < 1024) v *= qscale;
                    Cb[(size_t)row * N + col] = f2bf(v);
                }
            }
}

// ---------------------------------------------------------------------------
// Flash attention, no-max softmax (scores bounded; scale+log2e folded into Q
// by the projection epilogue).  QKVp: [8192][3072] bf16, Q cols 0..1023
// (pre-scaled), K cols 1024..2047.  Vt: [bh*64+d][k'] (key-permuted).
// Block: 4 waves x 32 q-rows = 128-row strip; each block does strips j, 7-j.
// v4: K/V tiles double-buffered, prefetch-before-compute (neutral, kept).
// v6: XCD swizzle -- the 4 j-blocks sharing one head's K/V were 128 linear
// ids apart (all on different XCDs); remap makes them consecutive on one XCD.
// ---------------------------------------------------------------------------
__global__ __launch_bounds__(256) void attn_kernel(
    const u16* __restrict__ QKVp, const u16* __restrict__ Vt,
    const int* __restrict__ lens, u16* __restrict__ O) {
    int id0 = blockIdx.x + (blockIdx.y << 7);   // x-fastest linear id, 512
    int nid = ((id0 & 7) << 6) + (id0 >> 3);    // XCD-contiguous remap
    int bh = nid >> 2;
    int j = nid & 3;             // strip pair: j and 7-j
    int b = bh >> 4, h = bh & 15;
    int len = lens[b];
    int cap = (len - 1) >> 6;    // last key tile with any valid key
    int tid = threadIdx.x, lane = tid & 63, w = tid >> 6;
    int quad = lane >> 4, l15 = lane & 15;

    __shared__ __align__(16) u16 sK[2][64 * 64];   // [key][d], seg-swizzled
    __shared__ __align__(16) u16 sV[2][64 * 64];   // [d][k'],  seg-swizzled
    __shared__ __align__(16) u16 sP[4 * 2048];     // per-wave 32x64 bf16 P
    u16* sPw = &sP[w << 11];

    int lrow = lane >> 3;       // 0..7: row within an 8-row staging chunk
    int lseg = lane & 7;

    // stage K and Vt tiles for key-tile kt into buffer buf (async LDS-DMA)
    auto stage = [&](int kt, int buf) {
        int k0g = kt << 6;
#pragma unroll
        for (int i = 0; i < 2; ++i) {
            int row = (w << 4) + (i << 3) + lrow;      // key row / d row
            int gs = lseg ^ (row & 7);
            gload_lds16(QKVp + (size_t)((b << 10) + k0g + row) * 3072
                           + 1024 + (h << 6) + (gs << 3),
                        &sK[buf][((w << 1) + i) << 9]);
            gload_lds16(Vt + (size_t)((bh << 6) + row) * 1024
                           + k0g + (gs << 3),
                        &sV[buf][((w << 1) + i) << 9]);
        }
    };

    fx4 zero = {0.0f, 0.0f, 0.0f, 0.0f};

#pragma unroll
    for (int phase = 0; phase < 2; ++phase) {
        int s = phase ? (7 - j) : j;
        int q0 = s << 7;
        int wq0 = q0 + (w << 5);
        int ktend_blk = min((q0 + 127) >> 6, cap);
        int ktend_w   = min((wq0 + 31) >> 6, cap);

        // Q fragments in registers for the whole strip
        short8 qf[2][2];
#pragma unroll
        for (int mt = 0; mt < 2; ++mt)
#pragma unroll
            for (int kk = 0; kk < 2; ++kk) {
                int qrow = (b << 10) + wq0 + (mt << 4) + l15;
                qf[mt][kk] = *(const short8*)(QKVp + (size_t)qrow * 3072
                              + (h << 6) + (kk << 5) + (quad << 3));
            }

        fx4 oacc[2][4];
        float lsum[2][4];
#pragma unroll
        for (int mt = 0; mt < 2; ++mt)
#pragma unroll
            for (int nt = 0; nt < 4; ++nt) oacc[mt][nt] = zero;
#pragma unroll
        for (int mt = 0; mt < 2; ++mt)
#pragma unroll
            for (int r = 0; r < 4; ++r) lsum[mt][r] = 0.0f;

        // prologue: tile 0 into buf 0, drain, visible to all
        stage(0, 0);
        __syncthreads();

        for (int kt = 0; kt <= ktend_blk; ++kt) {
            int cb = kt & 1;
            // prefetch next tile into the other buffer (hidden under compute)
            if (kt < ktend_blk) stage(kt + 1, cb ^ 1);

            if (kt <= ktend_w) {
                int k0g = kt << 6;
                // --- S = Q K^T ---
                fx4 sacc[2][4];
#pragma unroll
                for (int mt = 0; mt < 2; ++mt)
#pragma unroll
                    for (int nt = 0; nt < 4; ++nt) sacc[mt][nt] = zero;
#pragma unroll
                for (int kk = 0; kk < 2; ++kk) {
                    int seg = (kk << 2) + quad;
                    short8 kf[4];
#pragma unroll
                    for (int nt = 0; nt < 4; ++nt) {
                        int row = (nt << 4) + l15;
                        kf[nt] = *(const short8*)&sK[cb][(row << 6)
                                   + (((seg ^ (row & 7)) & 7) << 3)];
                    }
#pragma unroll
                    for (int mt = 0; mt < 2; ++mt)
#pragma unroll
                        for (int nt = 0; nt < 4; ++nt)
                            sacc[mt][nt] = mfma16(qf[mt][kk], kf[nt], sacc[mt][nt]);
                }

                // --- masks (boundary tiles only) ---
                bool needm = ((k0g + 63) > wq0) || ((k0g + 64) > len);
                if (needm) {
#pragma unroll
                    for (int mt = 0; mt < 2; ++mt)
#pragma unroll
                        for (int nt = 0; nt < 4; ++nt) {
                            int kg = k0g + (nt << 4) + l15;
#pragma unroll
                            for (int r = 0; r < 4; ++r) {
                                int qr = wq0 + (mt << 4) + (quad << 2) + r;
                                if (kg > qr || kg >= len)
                                    sacc[mt][nt][r] = -30000.0f;
                            }
                        }
                }

                // --- p = exp2(s), accumulate l, pack P to LDS ---
#pragma unroll
                for (int mt = 0; mt < 2; ++mt) {
#pragma unroll
                    for (int nt = 0; nt < 4; ++nt)
#pragma unroll
                        for (int r = 0; r < 4; ++r)
                            sacc[mt][nt][r] = fast_exp2(sacc[mt][nt][r]);
#pragma unroll
                    for (int r = 0; r < 4; ++r) {
                        lsum[mt][r] += (sacc[mt][0][r] + sacc[mt][1][r])
                                     + (sacc[mt][2][r] + sacc[mt][3][r]);
                        int row = (mt << 4) + (quad << 2) + r;
                        u32 lo = pack_bf2(sacc[mt][0][r], sacc[mt][1][r]);
                        u32 hi = pack_bf2(sacc[mt][2][r], sacc[mt][3][r]);
                        uint2 pv; pv.x = lo; pv.y = hi;
                        int addr = (row << 6)
                                 + (((((l15 >> 1)) ^ (row & 7)) & 7) << 3)
                                 + ((l15 & 1) << 2);
                        *(uint2*)&sPw[addr] = pv;
                    }
                }
                // sP is wave-private -> only need LDS-op completion, no barrier
                __builtin_amdgcn_s_waitcnt(0xC07F);  // lgkmcnt(0)

                // --- O += P V ---
#pragma unroll
                for (int kk = 0; kk < 2; ++kk) {
                    int seg = (kk << 2) + quad;
                    short8 vf[4], pf[2];
#pragma unroll
                    for (int nt = 0; nt < 4; ++nt) {
                        int row = (nt << 4) + l15;
                        vf[nt] = *(const short8*)&sV[cb][(row << 6)
                                   + (((seg ^ (row & 7)) & 7) << 3)];
                    }
#pragma unroll
                    for (int mt = 0; mt < 2; ++mt) {
                        int row = (mt << 4) + l15;
                        pf[mt] = *(const short8*)&sPw[(row << 6)
                                   + (((seg ^ (row & 7)) & 7) << 3)];
                    }
#pragma unroll
                    for (int mt = 0; mt < 2; ++mt)
#pragma unroll
                        for (int nt = 0; nt < 4; ++nt)
                            oacc[mt][nt] = mfma16(pf[mt], vf[nt], oacc[mt][nt]);
                }
            }
            // one barrier per tile: (a) all readers of buf cb are done before
            // it is re-staged at kt+2; (b) drains the kt+1 prefetch (vmcnt 0)
            // after it had the whole compute phase to fly.
            __syncthreads();
        }

        // --- reduce l across the 16 lanes of each quad, normalize, write ---
#pragma unroll
        for (int mt = 0; mt < 2; ++mt)
#pragma unroll
            for (int r = 0; r < 4; ++r) {
                float v = lsum[mt][r];
                v += __shfl_xor(v, 1, 64);
                v += __shfl_xor(v, 2, 64);
                v += __shfl_xor(v, 4, 64);
                v += __shfl_xor(v, 8, 64);
                lsum[mt][r] = __builtin_amdgcn_rcpf(v);
            }
#pragma unroll
        for (int mt = 0; mt < 2; ++mt)
#pragma unroll
            for (int nt = 0; nt < 4; ++nt)
#pragma unroll
                for (int r = 0; r < 4; ++r) {
                    int row = (b << 10) + wq0 + (mt << 4) + (quad << 2) + r;
                    int col = (h << 6) + (nt << 4) + l15;
                    O[((size_t)row << 10) + col] =
                        f2bf(oacc[mt][nt][r] * lsum[mt][r]);
                }
    }
}

// ---------------------------------------------------------------------------
extern "C" void kernel_launch(void* const* d_in, const int* in_sizes, int n_in,
                              void* d_out, int out_size, void* d_ws, size_t ws_size,
                              hipStream_t stream) {
    (void)in_sizes; (void)n_in; (void)out_size; (void)ws_size;
    const float* x    = (const float*)d_in[0];
    const int*   lens = (const int*)d_in[2];
    const float* Wq   = (const float*)d_in[3];
    const float* bq   = (const float*)d_in[4];
    const float* Wkv  = (const float*)d_in[5];
    const float* bkv  = (const float*)d_in[6];
    const float* Wo   = (const float*)d_in[7];
    const float* bo   = (const float*)d_in[8];
    const float* gam  = (const float*)d_in[9];
    const float* bet  = (const float*)d_in[10];
    float* out = (float*)d_out;

    char* w = (char*)d_ws;
    u16* xln_b  = (u16*)w;  w += (size_t)8192 * 1024 * 2;   // 16 MB: LN out (GEMM A + bf16 residual)
    u16* Wall_t = (u16*)w;  w += (size_t)4096 * 1024 * 2;   //  8 MB: [Wq^T | Wkv^T | Wo^T]
    u16* QKVp   = (u16*)w;  w += (size_t)8192 * 3072 * 2;   // 48 MB: Q(scaled)|K (V cols unused)
    u16* Vt     = (u16*)w;  w += (size_t)8192 * 1024 * 2;   // 16 MB: V transposed + key-permuted
    u16* AO     = (u16*)w;  w += (size_t)8192 * 1024 * 2;   // 16 MB: attention out
    // total 104 MB

    ln_wt_kernel<<<6144, 256, 0, stream>>>(x, gam, bet, xln_b, Wq, Wkv, Wo, Wall_t);
    gemm_bt<0, 4><<<dim3(24, 64), 256, 0, stream>>>(xln_b, Wall_t, bq, bkv,
        nullptr, nullptr, QKVp, Vt, 8192, 3072, 1024, 0.125f * LOG2E);
    attn_kernel<<<dim3(128, 4), 256, 0, stream>>>(QKVp, Vt, lens, AO);
    gemm_bt<1, 4><<<dim3(8, 64), 256, 0, stream>>>(AO, Wall_t + (size_t)3072 * 1024,
        bo, nullptr, xln_b, out, nullptr, nullptr, 8192, 1024, 1024, 1.0f);
}